// Round 10
// baseline (388.996 us; speedup 1.0000x reference)
//
#include <hip/hip_runtime.h>
#include <hip/hip_bf16.h>
#include <stdint.h>

// PhaseAttention on MI355X, round 9:
//  - GEMMs/packs: byte-identical to proven round-4 state (194us, 46.5 MfmaUtil).
//  - attn: V-RESIDENT restructure. Pass 1 stages K AND transposed V per chunk
//    (V window = 6 chunks = 108KB stays resident; total LDS 144KB). Pass 2
//    has ZERO barriers and ZERO global loads: per-wave private Ps write ->
//    in-wave lgkmcnt -> PV MFMA from resident Vts. Removes 6 barrier-pairs
//    and ~32MB duplicate L2 reads vs round 8.
//
//   A1[8192][2048] bf16 = [xr | xi] from z
//   Bp[8192][2048] bf16 = packed B^T rows for {q,k,v,o} x {re,im} with signs
//   C1[8192][6144] bf16 = A1 x Bp[0:6144]
//   attention (banded, 320 keys/query) -> A2 (=A1 buffer)
//   out[8192][1024][2] f32 = A2 x Bp[6144:8192]

typedef __attribute__((ext_vector_type(8))) short bf16x8;
typedef __attribute__((ext_vector_type(8))) unsigned short u16x8;
typedef __attribute__((ext_vector_type(4))) float f32x4;

#define PA_SCALE 0.125f
#define UNR _Pragma("unroll")

__device__ __forceinline__ unsigned short f2bf(float f) {
  unsigned int u = __builtin_bit_cast(unsigned int, f);
  u += 0x7fffu + ((u >> 16) & 1u);
  return (unsigned short)(u >> 16);
}

#define GLD16(gp, lp)                                          \
  __builtin_amdgcn_global_load_lds(                            \
      (const __attribute__((address_space(1))) void*)(gp),     \
      (__attribute__((address_space(3))) void*)(lp), 16, 0, 0)

// ---------------- pack A: z [8192][1024][2] f32 -> A1 [8192][2048] bf16 ----
__global__ __launch_bounds__(256) void pa_pack_A(const float* __restrict__ z,
                                                 unsigned short* __restrict__ A1) {
  int idx = (blockIdx.x * 256 + threadIdx.x) * 8;
  int m = idx >> 10, d = idx & 1023;
  const float2* zp = (const float2*)z + idx;
  u16x8 re, im;
  UNR for (int j = 0; j < 8; ++j) {
    float2 f = zp[j];
    re[j] = f2bf(f.x);
    im[j] = f2bf(f.y);
  }
  *(u16x8*)(A1 + (size_t)m * 2048 + d)        = re;
  *(u16x8*)(A1 + (size_t)m * 2048 + 1024 + d) = im;
}

// ---------------- pack B: 8 weight mats -> Bp [8192][2048] bf16 ------------
__global__ __launch_bounds__(256) void pa_pack_B(
    const float* __restrict__ Wq_r, const float* __restrict__ Wq_i,
    const float* __restrict__ Wk_r, const float* __restrict__ Wk_i,
    const float* __restrict__ Wv_r, const float* __restrict__ Wv_i,
    const float* __restrict__ Wo_r, const float* __restrict__ Wo_i,
    unsigned short* __restrict__ Bp) {
  int idx = (blockIdx.x * 256 + threadIdx.x) * 8;
  int n = idx >> 10, d = idx & 1023;
  int proj = n >> 11, part = (n >> 10) & 1, o = n & 1023;
  const float* Wr; const float* Wi;
  if (proj == 0)      { Wr = Wq_r; Wi = Wq_i; }
  else if (proj == 1) { Wr = Wk_r; Wi = Wk_i; }
  else if (proj == 2) { Wr = Wv_r; Wi = Wv_i; }
  else                { Wr = Wo_r; Wi = Wo_i; }
  const float* pr = Wr + (size_t)o * 1024 + d;
  const float* pi = Wi + (size_t)o * 1024 + d;
  u16x8 lo, hi;
  UNR for (int j = 0; j < 8; ++j) {
    float r = pr[j], im = pi[j];
    if (part == 0) { lo[j] = f2bf(r);  hi[j] = f2bf(-im); }
    else           { lo[j] = f2bf(im); hi[j] = f2bf(r);  }
  }
  *(u16x8*)(Bp + (size_t)n * 2048 + d)        = lo;
  *(u16x8*)(Bp + (size_t)n * 2048 + 1024 + d) = hi;
}

// ---------------- 256x256 8-phase GEMM (round-2/4 proven, 16x16x32) --------
#define BARR()                              \
  do {                                      \
    __builtin_amdgcn_s_barrier();           \
    __builtin_amdgcn_sched_barrier(0);      \
  } while (0)

#define READ_A(P, MH)                                                         \
  UNR for (int i = 0; i < 4; ++i)                                             \
    UNR for (int ks = 0; ks < 2; ++ks)                                        \
      af[i][ks] = *(const bf16x8*)&lds[P][MH][aoff + i * 1024 +               \
                                              ((ks * 32 + koff) ^ cxor)];

#define READ_B(P, NH, DST)                                                    \
  UNR for (int j = 0; j < 2; ++j)                                             \
    UNR for (int ks = 0; ks < 2; ++ks)                                        \
      DST[j][ks] = *(const bf16x8*)&lds[P][2 + (NH)][boff + j * 1024 +        \
                                                     ((ks * 32 + koff) ^ cxor)];

#define MFMA_Q(MB, NB, BF)                                                    \
  UNR for (int ks = 0; ks < 2; ++ks)                                          \
    UNR for (int i = 0; i < 4; ++i)                                           \
      UNR for (int j = 0; j < 2; ++j)                                         \
        acc[(MB) + i][(NB) + j] = __builtin_amdgcn_mfma_f32_16x16x32_bf16(    \
            af[i][ks], BF[j][ks], acc[(MB) + i][(NB) + j], 0, 0, 0);

#define TILE(P, T)                                                            \
  {                                                                           \
    READ_A(P, 0);                                                             \
    READ_B(P, 0, b0);                                                         \
    stageB(0, (T) + 1);                                                       \
    BARR();                                                                   \
    __builtin_amdgcn_s_setprio(1);                                            \
    MFMA_Q(0, 0, b0);                                                         \
    __builtin_amdgcn_s_setprio(0);                                            \
    BARR();                                                                   \
    READ_B(P, 1, b1);                                                         \
    stageA(0, (T) + 2);                                                       \
    BARR();                                                                   \
    __builtin_amdgcn_s_setprio(1);                                            \
    MFMA_Q(0, 2, b1);                                                         \
    __builtin_amdgcn_s_setprio(0);                                            \
    BARR();                                                                   \
    READ_A(P, 1);                                                             \
    stageB(1, (T) + 2);                                                       \
    BARR();                                                                   \
    __builtin_amdgcn_s_setprio(1);                                            \
    MFMA_Q(4, 2, b1);                                                         \
    __builtin_amdgcn_s_setprio(0);                                            \
    BARR();                                                                   \
    stageA(1, (T) + 2);                                                       \
    BARR();                                                                   \
    __builtin_amdgcn_s_setprio(1);                                            \
    MFMA_Q(4, 0, b0);                                                         \
    __builtin_amdgcn_s_setprio(0);                                            \
    asm volatile("s_waitcnt vmcnt(6)" ::: "memory");                          \
    __builtin_amdgcn_sched_barrier(0);                                        \
    BARR();                                                                   \
  }

template <int EPI>
__global__ __launch_bounds__(512, 2) void pa_gemm8(
    const unsigned short* __restrict__ A,
    const unsigned short* __restrict__ B,
    void* __restrict__ Cout, int K, int N) {
  __shared__ unsigned short lds[2][4][128 * 64];   // 128 KiB

  const int tid = threadIdx.x;
  const int lane = tid & 63, wid = tid >> 6;
  const int wm = wid >> 2, wn = wid & 3;
  const int lr = lane & 15, lh = lane >> 4;

  const int nwg = gridDim.x * gridDim.y;
  const int wg = blockIdx.y * gridDim.x + blockIdx.x;
  const int cpx = nwg >> 3;
  const int swz = (wg & 7) * cpx + (wg >> 3);
  const int bx = swz % gridDim.x, by = swz / gridDim.x;
  const int tm0 = by * 256, tn0 = bx * 256;

  const int NT = K >> 6;

  const int srow = lane >> 3;
  const int scolS = ((lane & 7) ^ srow) * 8;

  auto stageA = [&](int half, int ts) {
    int t = ts < NT ? ts : ts - NT;
    const unsigned short* g0 = A + (size_t)(tm0 + half * 128) * K + t * 64 + scolS;
    unsigned short* l0 = &lds[ts & 1][half][0];
    UNR for (int c = 0; c < 2; ++c) {
      int chunk = wid * 2 + c;
      GLD16(g0 + (size_t)(chunk * 8 + srow) * K, l0 + chunk * 512);
    }
  };
  auto stageB = [&](int half, int ts) {
    int t = ts < NT ? ts : ts - NT;
    const unsigned short* g0 = B + (size_t)(tn0 + half * 128) * K + t * 64 + scolS;
    unsigned short* l0 = &lds[ts & 1][2 + half][0];
    UNR for (int c = 0; c < 2; ++c) {
      int chunk = wid * 2 + c;
      GLD16(g0 + (size_t)(chunk * 8 + srow) * K, l0 + chunk * 512);
    }
  };

  const int aoff = (wm * 64 + lr) * 64;
  const int boff = (wn * 32 + lr) * 64;
  const int koff = lh * 8;
  const int cxor = (lr & 7) * 8;

  f32x4 acc[8][4];
  f32x4 zero4 = {0.f, 0.f, 0.f, 0.f};
  UNR for (int i = 0; i < 8; ++i)
    UNR for (int j = 0; j < 4; ++j) acc[i][j] = zero4;

  bf16x8 af[4][2], b0[2][2], b1[2][2];

  stageA(0, 0); stageB(0, 0); stageB(1, 0); stageA(1, 0);
  stageA(0, 1); stageB(1, 1); stageA(1, 1);
  asm volatile("s_waitcnt vmcnt(6)" ::: "memory");
  __builtin_amdgcn_sched_barrier(0);
  __builtin_amdgcn_s_barrier();
  __builtin_amdgcn_sched_barrier(0);

  for (int t = 0; t < NT; t += 2) {
    TILE(0, t);
    TILE(1, t + 1);
  }

  UNR for (int mh = 0; mh < 2; ++mh)
    UNR for (int i = 0; i < 4; ++i)
      UNR for (int nh = 0; nh < 2; ++nh)
        UNR for (int j = 0; j < 2; ++j)
          UNR for (int r = 0; r < 4; ++r) {
            int row = tm0 + mh * 128 + wm * 64 + i * 16 + lh * 4 + r;
            int col = tn0 + nh * 128 + wn * 32 + j * 16 + lr;
            float v = acc[mh * 4 + i][nh * 2 + j][r];
            if (EPI == 0) {
              ((unsigned short*)Cout)[(size_t)row * N + col] = f2bf(v);
            } else {
              int part = col >> 10, dd = col & 1023;
              ((float*)Cout)[((size_t)row * 1024 + dd) * 2 + part] = v;
            }
          }
}

// ---------------- banded attention: V-resident, barrier-free pass 2 --------
// Grid 1024 = b(2) x h(16) x nc(16) x half(2); 512 thr = 8 waves x 16 queries.
// Pass 1: per chunk c (0..5): stage K_c (rotating) + V_c^T (resident) in one
// barrier pair; QK MFMA arms (wave group A: chunks 0-4, group B: 1-5).
// Pass 2: no barriers, no global: Ps (wave-private) -> PV from resident Vts.
#define QK1(SI)                                                               \
  UNR for (int kk = 0; kk < 2; ++kk)                                          \
    UNR for (int f = 0; f < 4; ++f) {                                         \
      bf16x8 br = *(const bf16x8*)&Ks[0][f * 16 + lr][kk * 32 + lh * 8];      \
      bf16x8 bi = *(const bf16x8*)&Ks[1][f * 16 + lr][kk * 32 + lh * 8];      \
      sac[SI][f] = __builtin_amdgcn_mfma_f32_16x16x32_bf16(qfr[kk], br,       \
                                                           sac[SI][f], 0, 0, 0); \
      sac[SI][f] = __builtin_amdgcn_mfma_f32_16x16x32_bf16(qfi[kk], bi,       \
                                                           sac[SI][f], 0, 0, 0); \
    }

__global__ __launch_bounds__(512) void pa_attn(const unsigned short* __restrict__ C1,
                                               unsigned short* __restrict__ A2) {
  __shared__ unsigned short Ks[2][64][72];        // [re/im][key][hd]   18 KB
  __shared__ unsigned short Vts[6][2][64][72];    // [c][re/im][hd][key] 108 KB
  __shared__ unsigned short Ps[8][16][72];        // per-wave P stripe  18 KB

  int bid = blockIdx.x;
  int half = bid & 1, nc = (bid >> 1) & 15, h = (bid >> 5) & 15, b = bid >> 9;
  int tid = threadIdx.x;
  int l = tid & 63, wv = tid >> 6;
  int lr = l & 15, lh = l >> 4;
  int base = wv >> 2;                         // wave's first chunk (0 or 1)

  const int C1LD = 6144;
  const int rowB = b * 4096;
  const int colQr = h * 64,        colQi = 1024 + h * 64;
  const int colKr = 2048 + h * 64, colKi = 3072 + h * 64;
  const int colVr = 4096 + h * 64, colVi = 5120 + h * 64;
  const int q0 = half * 128;                  // block-local first query
  const int qw = q0 + wv * 16;                // wave-local first query

  bf16x8 qfr[2], qfi[2];
  {
    const unsigned short* pr = C1 + (size_t)(rowB + nc * 256 + qw + lr) * C1LD + colQr;
    const unsigned short* pi = C1 + (size_t)(rowB + nc * 256 + qw + lr) * C1LD + colQi;
    qfr[0] = *(const bf16x8*)(pr + lh * 8);
    qfr[1] = *(const bf16x8*)(pr + 32 + lh * 8);
    qfi[0] = *(const bf16x8*)(pi + lh * 8);
    qfi[1] = *(const bf16x8*)(pi + 32 + lh * 8);
  }

  f32x4 zero4 = {0.f, 0.f, 0.f, 0.f};
  f32x4 sac[5][4];
#pragma unroll
  for (int c = 0; c < 5; ++c)
#pragma unroll
    for (int f = 0; f < 4; ++f) sac[c][f] = zero4;

  // ---- pass 1: stage K_c + V_c^T per chunk; QK arms ----
#pragma unroll
  for (int c = 0; c < 6; ++c) {
    __syncthreads();
#pragma unroll
    for (int s = 0; s < 2; ++s) {
      int seg = s * 512 + tid;                 // 0..1023
      int arr = seg >> 9, row = (seg >> 3) & 63, sg = seg & 7;
      int kj = q0 + c * 64 + row;
      int tok = (nc - 1) * 256 + kj; if (tok < 0) tok = 0;  // masked anyway
      const unsigned short* rp = C1 + (size_t)(rowB + tok) * C1LD;
      *(bf16x8*)&Ks[arr][row][sg * 8] =
          *(const bf16x8*)(rp + (arr ? colKi : colKr) + sg * 8);
      bf16x8 v = *(const bf16x8*)(rp + (arr ? colVi : colVr) + sg * 8);
#pragma unroll
      for (int j = 0; j < 8; ++j) Vts[c][arr][sg * 8 + j][row] = (unsigned short)v[j];
    }
    __syncthreads();
    if (wv < 4) { if (c < 5) { QK1(c); } }
    else        { if (c >= 1) { QK1(c - 1); } }
  }

  // ---- mask + scale + softmax (kj uses actual chunk = si + base) ----
  float mx[4] = {-1e30f, -1e30f, -1e30f, -1e30f};
#pragma unroll
  for (int si = 0; si < 5; ++si)
#pragma unroll
    for (int f = 0; f < 4; ++f)
#pragma unroll
      for (int r = 0; r < 4; ++r) {
        int qi_ = qw + lh * 4 + r;
        int kj  = q0 + (si + base) * 64 + f * 16 + lr;
        bool valid = (kj > qi_) && (kj <= qi_ + 256) && (nc > 0 || kj >= 256);
        float s = valid ? sac[si][f][r] * PA_SCALE : -1e30f;
        sac[si][f][r] = s;
        mx[r] = fmaxf(mx[r], s);
      }
#pragma unroll
  for (int r = 0; r < 4; ++r)
#pragma unroll
    for (int d = 1; d < 16; d <<= 1) mx[r] = fmaxf(mx[r], __shfl_xor(mx[r], d));

  float sm[4] = {0.f, 0.f, 0.f, 0.f};
#pragma unroll
  for (int si = 0; si < 5; ++si)
#pragma unroll
    for (int f = 0; f < 4; ++f)
#pragma unroll
      for (int r = 0; r < 4; ++r) {
        float p = __expf(sac[si][f][r] - mx[r]);
        sac[si][f][r] = p;
        sm[r] += p;
      }
#pragma unroll
  for (int r = 0; r < 4; ++r)
#pragma unroll
    for (int d = 1; d < 16; d <<= 1) sm[r] += __shfl_xor(sm[r], d);
  float inv[4];
#pragma unroll
  for (int r = 0; r < 4; ++r) inv[r] = 1.0f / sm[r];

  // ---- pass 2: barrier-free P x V from resident Vts ----
  f32x4 oac[2][4];
#pragma unroll
  for (int p = 0; p < 2; ++p)
#pragma unroll
    for (int f = 0; f < 4; ++f) oac[p][f] = zero4;

  // wave's chunk si lives at Vts[si + base]; base is a runtime LDS offset
  const unsigned short* vb = &Vts[0][0][0][0] + base * 9216;

#pragma unroll
  for (int si = 0; si < 5; ++si) {
#pragma unroll
    for (int f = 0; f < 4; ++f)
#pragma unroll
      for (int r = 0; r < 4; ++r)
        Ps[wv][lh * 4 + r][f * 16 + lr] = f2bf(sac[si][f][r]);

    bf16x8 pa0 = *(const bf16x8*)&Ps[wv][lr][lh * 8];
    bf16x8 pa1 = *(const bf16x8*)&Ps[wv][lr][32 + lh * 8];
#pragma unroll
    for (int kk = 0; kk < 2; ++kk) {
      bf16x8 pak = kk ? pa1 : pa0;
#pragma unroll
      for (int fc = 0; fc < 4; ++fc) {
        const unsigned short* pvr =
            vb + si * 9216 + (fc * 16 + lr) * 72 + kk * 32 + lh * 8;
        bf16x8 vr = *(const bf16x8*)pvr;
        bf16x8 vi = *(const bf16x8*)(pvr + 4608);
        oac[0][fc] = __builtin_amdgcn_mfma_f32_16x16x32_bf16(pak, vr, oac[0][fc], 0, 0, 0);
        oac[1][fc] = __builtin_amdgcn_mfma_f32_16x16x32_bf16(pak, vi, oac[1][fc], 0, 0, 0);
      }
    }
  }

  // ---- write O ----
#pragma unroll
  for (int fc = 0; fc < 4; ++fc)
#pragma unroll
    for (int r = 0; r < 4; ++r) {
      int m  = rowB + nc * 256 + qw + lh * 4 + r;
      int hd = fc * 16 + lr;
      A2[(size_t)m * 2048 + h * 64 + hd]        = f2bf(oac[0][fc][r] * inv[r]);
      A2[(size_t)m * 2048 + 1024 + h * 64 + hd] = f2bf(oac[1][fc][r] * inv[r]);
    }
}

// ---------------------------------------------------------------------------
extern "C" void kernel_launch(void* const* d_in, const int* in_sizes, int n_in,
                              void* d_out, int out_size, void* d_ws, size_t ws_size,
                              hipStream_t stream) {
  const float* z = (const float*)d_in[0];
  unsigned short* A1 = (unsigned short*)d_ws;                          // 32 MB
  unsigned short* Bp = (unsigned short*)((char*)d_ws + 33554432ull);   // 32 MB
  unsigned short* C1 = (unsigned short*)((char*)d_ws + 67108864ull);   // 96 MB
  float* out = (float*)d_out;

  pa_pack_A<<<4096, 256, 0, stream>>>(z, A1);
  pa_pack_B<<<4096, 256, 0, stream>>>(
      (const float*)d_in[1], (const float*)d_in[2],
      (const float*)d_in[3], (const float*)d_in[4],
      (const float*)d_in[5], (const float*)d_in[6],
      (const float*)d_in[7], (const float*)d_in[8], Bp);
  // QKV projection: [8192x2048] x [2048x6144] -> C1 bf16
  pa_gemm8<0><<<dim3(24, 32), 512, 0, stream>>>(A1, Bp, C1, 2048, 6144);
  // banded attention -> A2 (reuses A1 buffer)
  pa_attn<<<1024, 512, 0, stream>>>(C1, A1);
  // output projection: [8192x2048] x [2048x2048] -> out f32 interleaved
  pa_gemm8<1><<<dim3(8, 32), 512, 0, stream>>>(A1, Bp + (size_t)6144 * 2048, out,
                                               2048, 2048);
}

// Round 11
// 380.798 us; speedup vs baseline: 1.0215x; 1.0215x over previous
//
#include <hip/hip_runtime.h>
#include <hip/hip_bf16.h>
#include <stdint.h>

// PhaseAttention on MI355X, round 10:
//  - GEMM1/packs structure: proven round-4 state.
//  - attn: round-8 8-wave shared-staging version (equal-best, 54KB LDS).
//  - NEW: Bp o-projection rows permuted to 6144 + o*2 + part so GEMM2's
//    f32 epilogue stores are lane-consecutive (was stride-8B interleave,
//    half-utilized 128B spans on 64MB of writes).
//
//   A1[8192][2048] bf16 = [xr | xi] from z
//   Bp[8192][2048] bf16 = packed B^T rows; o-proj rows interleaved (o*2+part)
//   C1[8192][6144] bf16 = A1 x Bp[0:6144]
//   attention (banded, 320 keys/query) -> A2 (=A1 buffer)
//   out[8192][2048] f32 = A2 x Bp[6144:8192]  (flat, coalesced)

typedef __attribute__((ext_vector_type(8))) short bf16x8;
typedef __attribute__((ext_vector_type(8))) unsigned short u16x8;
typedef __attribute__((ext_vector_type(4))) float f32x4;

#define PA_SCALE 0.125f
#define UNR _Pragma("unroll")

__device__ __forceinline__ unsigned short f2bf(float f) {
  unsigned int u = __builtin_bit_cast(unsigned int, f);
  u += 0x7fffu + ((u >> 16) & 1u);
  return (unsigned short)(u >> 16);
}

#define GLD16(gp, lp)                                          \
  __builtin_amdgcn_global_load_lds(                            \
      (const __attribute__((address_space(1))) void*)(gp),     \
      (__attribute__((address_space(3))) void*)(lp), 16, 0, 0)

// ---------------- pack A: z [8192][1024][2] f32 -> A1 [8192][2048] bf16 ----
__global__ __launch_bounds__(256) void pa_pack_A(const float* __restrict__ z,
                                                 unsigned short* __restrict__ A1) {
  int idx = (blockIdx.x * 256 + threadIdx.x) * 8;
  int m = idx >> 10, d = idx & 1023;
  const float2* zp = (const float2*)z + idx;
  u16x8 re, im;
  UNR for (int j = 0; j < 8; ++j) {
    float2 f = zp[j];
    re[j] = f2bf(f.x);
    im[j] = f2bf(f.y);
  }
  *(u16x8*)(A1 + (size_t)m * 2048 + d)        = re;
  *(u16x8*)(A1 + (size_t)m * 2048 + 1024 + d) = im;
}

// ---------------- pack B: 8 weight mats -> Bp [8192][2048] bf16 ------------
// proj 0..2 (q,k,v): row n = proj*2048 + part*1024 + o (as before).
// proj 3   (o)     : row n = 6144 + o*2 + part  -> GEMM2 col == flat out col.
__global__ __launch_bounds__(256) void pa_pack_B(
    const float* __restrict__ Wq_r, const float* __restrict__ Wq_i,
    const float* __restrict__ Wk_r, const float* __restrict__ Wk_i,
    const float* __restrict__ Wv_r, const float* __restrict__ Wv_i,
    const float* __restrict__ Wo_r, const float* __restrict__ Wo_i,
    unsigned short* __restrict__ Bp) {
  int idx = (blockIdx.x * 256 + threadIdx.x) * 8;
  int n = idx >> 10, d = idx & 1023;
  int proj = n >> 11, part = (n >> 10) & 1, o = n & 1023;
  const float* Wr; const float* Wi;
  if (proj == 0)      { Wr = Wq_r; Wi = Wq_i; }
  else if (proj == 1) { Wr = Wk_r; Wi = Wk_i; }
  else if (proj == 2) { Wr = Wv_r; Wi = Wv_i; }
  else                { Wr = Wo_r; Wi = Wo_i; }
  const float* pr = Wr + (size_t)o * 1024 + d;
  const float* pi = Wi + (size_t)o * 1024 + d;
  u16x8 lo, hi;
  UNR for (int j = 0; j < 8; ++j) {
    float r = pr[j], im = pi[j];
    if (part == 0) { lo[j] = f2bf(r);  hi[j] = f2bf(-im); }
    else           { lo[j] = f2bf(im); hi[j] = f2bf(r);  }
  }
  size_t nn = (proj < 3) ? (size_t)n : (size_t)(6144 + o * 2 + part);
  *(u16x8*)(Bp + nn * 2048 + d)        = lo;
  *(u16x8*)(Bp + nn * 2048 + 1024 + d) = hi;
}

// ---------------- 256x256 8-phase GEMM (round-2/4 proven, 16x16x32) --------
#define BARR()                              \
  do {                                      \
    __builtin_amdgcn_s_barrier();           \
    __builtin_amdgcn_sched_barrier(0);      \
  } while (0)

#define READ_A(P, MH)                                                         \
  UNR for (int i = 0; i < 4; ++i)                                             \
    UNR for (int ks = 0; ks < 2; ++ks)                                        \
      af[i][ks] = *(const bf16x8*)&lds[P][MH][aoff + i * 1024 +               \
                                              ((ks * 32 + koff) ^ cxor)];

#define READ_B(P, NH, DST)                                                    \
  UNR for (int j = 0; j < 2; ++j)                                             \
    UNR for (int ks = 0; ks < 2; ++ks)                                        \
      DST[j][ks] = *(const bf16x8*)&lds[P][2 + (NH)][boff + j * 1024 +        \
                                                     ((ks * 32 + koff) ^ cxor)];

#define MFMA_Q(MB, NB, BF)                                                    \
  UNR for (int ks = 0; ks < 2; ++ks)                                          \
    UNR for (int i = 0; i < 4; ++i)                                           \
      UNR for (int j = 0; j < 2; ++j)                                         \
        acc[(MB) + i][(NB) + j] = __builtin_amdgcn_mfma_f32_16x16x32_bf16(    \
            af[i][ks], BF[j][ks], acc[(MB) + i][(NB) + j], 0, 0, 0);

#define TILE(P, T)                                                            \
  {                                                                           \
    READ_A(P, 0);                                                             \
    READ_B(P, 0, b0);                                                         \
    stageB(0, (T) + 1);                                                       \
    BARR();                                                                   \
    __builtin_amdgcn_s_setprio(1);                                            \
    MFMA_Q(0, 0, b0);                                                         \
    __builtin_amdgcn_s_setprio(0);                                            \
    BARR();                                                                   \
    READ_B(P, 1, b1);                                                         \
    stageA(0, (T) + 2);                                                       \
    BARR();                                                                   \
    __builtin_amdgcn_s_setprio(1);                                            \
    MFMA_Q(0, 2, b1);                                                         \
    __builtin_amdgcn_s_setprio(0);                                            \
    BARR();                                                                   \
    READ_A(P, 1);                                                             \
    stageB(1, (T) + 2);                                                       \
    BARR();                                                                   \
    __builtin_amdgcn_s_setprio(1);                                            \
    MFMA_Q(4, 2, b1);                                                         \
    __builtin_amdgcn_s_setprio(0);                                            \
    BARR();                                                                   \
    stageA(1, (T) + 2);                                                       \
    BARR();                                                                   \
    __builtin_amdgcn_s_setprio(1);                                            \
    MFMA_Q(4, 0, b0);                                                         \
    __builtin_amdgcn_s_setprio(0);                                            \
    asm volatile("s_waitcnt vmcnt(6)" ::: "memory");                          \
    __builtin_amdgcn_sched_barrier(0);                                        \
    BARR();                                                                   \
  }

template <int EPI>
__global__ __launch_bounds__(512, 2) void pa_gemm8(
    const unsigned short* __restrict__ A,
    const unsigned short* __restrict__ B,
    void* __restrict__ Cout, int K, int N) {
  __shared__ unsigned short lds[2][4][128 * 64];   // 128 KiB

  const int tid = threadIdx.x;
  const int lane = tid & 63, wid = tid >> 6;
  const int wm = wid >> 2, wn = wid & 3;
  const int lr = lane & 15, lh = lane >> 4;

  const int nwg = gridDim.x * gridDim.y;
  const int wg = blockIdx.y * gridDim.x + blockIdx.x;
  const int cpx = nwg >> 3;
  const int swz = (wg & 7) * cpx + (wg >> 3);
  const int bx = swz % gridDim.x, by = swz / gridDim.x;
  const int tm0 = by * 256, tn0 = bx * 256;

  const int NT = K >> 6;

  const int srow = lane >> 3;
  const int scolS = ((lane & 7) ^ srow) * 8;

  auto stageA = [&](int half, int ts) {
    int t = ts < NT ? ts : ts - NT;
    const unsigned short* g0 = A + (size_t)(tm0 + half * 128) * K + t * 64 + scolS;
    unsigned short* l0 = &lds[ts & 1][half][0];
    UNR for (int c = 0; c < 2; ++c) {
      int chunk = wid * 2 + c;
      GLD16(g0 + (size_t)(chunk * 8 + srow) * K, l0 + chunk * 512);
    }
  };
  auto stageB = [&](int half, int ts) {
    int t = ts < NT ? ts : ts - NT;
    const unsigned short* g0 = B + (size_t)(tn0 + half * 128) * K + t * 64 + scolS;
    unsigned short* l0 = &lds[ts & 1][2 + half][0];
    UNR for (int c = 0; c < 2; ++c) {
      int chunk = wid * 2 + c;
      GLD16(g0 + (size_t)(chunk * 8 + srow) * K, l0 + chunk * 512);
    }
  };

  const int aoff = (wm * 64 + lr) * 64;
  const int boff = (wn * 32 + lr) * 64;
  const int koff = lh * 8;
  const int cxor = (lr & 7) * 8;

  f32x4 acc[8][4];
  f32x4 zero4 = {0.f, 0.f, 0.f, 0.f};
  UNR for (int i = 0; i < 8; ++i)
    UNR for (int j = 0; j < 4; ++j) acc[i][j] = zero4;

  bf16x8 af[4][2], b0[2][2], b1[2][2];

  stageA(0, 0); stageB(0, 0); stageB(1, 0); stageA(1, 0);
  stageA(0, 1); stageB(1, 1); stageA(1, 1);
  asm volatile("s_waitcnt vmcnt(6)" ::: "memory");
  __builtin_amdgcn_sched_barrier(0);
  __builtin_amdgcn_s_barrier();
  __builtin_amdgcn_sched_barrier(0);

  for (int t = 0; t < NT; t += 2) {
    TILE(0, t);
    TILE(1, t + 1);
  }

  UNR for (int mh = 0; mh < 2; ++mh)
    UNR for (int i = 0; i < 4; ++i)
      UNR for (int nh = 0; nh < 2; ++nh)
        UNR for (int j = 0; j < 2; ++j)
          UNR for (int r = 0; r < 4; ++r) {
            int row = tm0 + mh * 128 + wm * 64 + i * 16 + lh * 4 + r;
            int col = tn0 + nh * 128 + wn * 32 + j * 16 + lr;
            float v = acc[mh * 4 + i][nh * 2 + j][r];
            if (EPI == 0) {
              ((unsigned short*)Cout)[(size_t)row * N + col] = f2bf(v);
            } else {
              // Bp o-rows are permuted so col == flat output column.
              ((float*)Cout)[(size_t)row * N + col] = v;
            }
          }
}

// ---------------- banded attention: 128-query / 8-wave blocks (round 8) ----
#define QK1(SI)                                                               \
  UNR for (int kk = 0; kk < 2; ++kk)                                          \
    UNR for (int f = 0; f < 4; ++f) {                                         \
      bf16x8 br = *(const bf16x8*)&Ks[0][f * 16 + lr][kk * 32 + lh * 8];      \
      bf16x8 bi = *(const bf16x8*)&Ks[1][f * 16 + lr][kk * 32 + lh * 8];      \
      sac[SI][f] = __builtin_amdgcn_mfma_f32_16x16x32_bf16(qfr[kk], br,       \
                                                           sac[SI][f], 0, 0, 0); \
      sac[SI][f] = __builtin_amdgcn_mfma_f32_16x16x32_bf16(qfi[kk], bi,       \
                                                           sac[SI][f], 0, 0, 0); \
    }

#define PW1(SI)                                                               \
  UNR for (int f = 0; f < 4; ++f)                                             \
    UNR for (int r = 0; r < 4; ++r)                                           \
      Ps[wv][lh * 4 + r][f * 16 + lr] = f2bf(sac[SI][f][r]);

#define PV1()                                                                 \
  {                                                                           \
    bf16x8 pa0 = *(const bf16x8*)&Ps[wv][lr][lh * 8];                         \
    bf16x8 pa1 = *(const bf16x8*)&Ps[wv][lr][32 + lh * 8];                    \
    UNR for (int kk = 0; kk < 2; ++kk) {                                      \
      bf16x8 pak = kk ? pa1 : pa0;                                            \
      UNR for (int fc = 0; fc < 4; ++fc) {                                    \
        bf16x8 vr = *(const bf16x8*)&Vts[0][fc * 16 + lr][kk * 32 + lh * 8];  \
        bf16x8 vi = *(const bf16x8*)&Vts[1][fc * 16 + lr][kk * 32 + lh * 8];  \
        oac[0][fc] = __builtin_amdgcn_mfma_f32_16x16x32_bf16(pak, vr,         \
                                                             oac[0][fc], 0, 0, 0); \
        oac[1][fc] = __builtin_amdgcn_mfma_f32_16x16x32_bf16(pak, vi,         \
                                                             oac[1][fc], 0, 0, 0); \
      }                                                                       \
    }                                                                         \
  }

__global__ __launch_bounds__(512) void pa_attn(const unsigned short* __restrict__ C1,
                                               unsigned short* __restrict__ A2) {
  __shared__ unsigned short Ks[2][64][72];    // [re/im][key][hd]
  __shared__ unsigned short Vts[2][64][72];   // [re/im][hd][key] transposed
  __shared__ unsigned short Ps[8][16][72];    // per-wave P stripe

  int bid = blockIdx.x;
  int half = bid & 1, nc = (bid >> 1) & 15, h = (bid >> 5) & 15, b = bid >> 9;
  int tid = threadIdx.x;
  int l = tid & 63, wv = tid >> 6;
  int lr = l & 15, lh = l >> 4;
  int base = wv >> 2;                         // wave's first chunk (0 or 1)

  const int C1LD = 6144;
  const int rowB = b * 4096;
  const int colQr = h * 64,        colQi = 1024 + h * 64;
  const int colKr = 2048 + h * 64, colKi = 3072 + h * 64;
  const int colVr = 4096 + h * 64, colVi = 5120 + h * 64;
  const int q0 = half * 128;
  const int qw = q0 + wv * 16;

  bf16x8 qfr[2], qfi[2];
  {
    const unsigned short* pr = C1 + (size_t)(rowB + nc * 256 + qw + lr) * C1LD + colQr;
    const unsigned short* pi = C1 + (size_t)(rowB + nc * 256 + qw + lr) * C1LD + colQi;
    qfr[0] = *(const bf16x8*)(pr + lh * 8);
    qfr[1] = *(const bf16x8*)(pr + 32 + lh * 8);
    qfi[0] = *(const bf16x8*)(pi + lh * 8);
    qfi[1] = *(const bf16x8*)(pi + 32 + lh * 8);
  }

  f32x4 zero4 = {0.f, 0.f, 0.f, 0.f};
  f32x4 sac[5][4];
#pragma unroll
  for (int c = 0; c < 5; ++c)
#pragma unroll
    for (int f = 0; f < 4; ++f) sac[c][f] = zero4;

#pragma unroll
  for (int c = 0; c < 6; ++c) {
    __syncthreads();
#pragma unroll
    for (int s = 0; s < 2; ++s) {
      int seg = s * 512 + tid;
      int arr = seg >> 9, row = (seg >> 3) & 63, sg = seg & 7;
      int kj = q0 + c * 64 + row;
      int tok = (nc - 1) * 256 + kj; if (tok < 0) tok = 0;
      const unsigned short* src =
          C1 + (size_t)(rowB + tok) * C1LD + (arr ? colKi : colKr) + sg * 8;
      *(bf16x8*)&Ks[arr][row][sg * 8] = *(const bf16x8*)src;
    }
    __syncthreads();
    if (wv < 4) { if (c < 5) { QK1(c); } }
    else        { if (c >= 1) { QK1(c - 1); } }
  }

  float mx[4] = {-1e30f, -1e30f, -1e30f, -1e30f};
#pragma unroll
  for (int si = 0; si < 5; ++si)
#pragma unroll
    for (int f = 0; f < 4; ++f)
#pragma unroll
      for (int r = 0; r < 4; ++r) {
        int qi_ = qw + lh * 4 + r;
        int kj  = q0 + (si + base) * 64 + f * 16 + lr;
        bool valid = (kj > qi_) && (kj <= qi_ + 256) && (nc > 0 || kj >= 256);
        float s = valid ? sac[si][f][r] * PA_SCALE : -1e30f;
        sac[si][f][r] = s;
        mx[r] = fmaxf(mx[r], s);
      }
#pragma unroll
  for (int r = 0; r < 4; ++r)
#pragma unroll
    for (int d = 1; d < 16; d <<= 1) mx[r] = fmaxf(mx[r], __shfl_xor(mx[r], d));

  float sm[4] = {0.f, 0.f, 0.f, 0.f};
#pragma unroll
  for (int si = 0; si < 5; ++si)
#pragma unroll
    for (int f = 0; f < 4; ++f)
#pragma unroll
      for (int r = 0; r < 4; ++r) {
        float p = __expf(sac[si][f][r] - mx[r]);
        sac[si][f][r] = p;
        sm[r] += p;
      }
#pragma unroll
  for (int r = 0; r < 4; ++r)
#pragma unroll
    for (int d = 1; d < 16; d <<= 1) sm[r] += __shfl_xor(sm[r], d);
  float inv[4];
#pragma unroll
  for (int r = 0; r < 4; ++r) inv[r] = 1.0f / sm[r];

  f32x4 oac[2][4];
#pragma unroll
  for (int p = 0; p < 2; ++p)
#pragma unroll
    for (int f = 0; f < 4; ++f) oac[p][f] = zero4;

#pragma unroll
  for (int c = 0; c < 6; ++c) {
    __syncthreads();
#pragma unroll
    for (int s = 0; s < 2; ++s) {
      int seg = s * 512 + tid;
      int arr = seg >> 9, row = (seg >> 3) & 63, sg = seg & 7;
      int kj = q0 + c * 64 + row;
      int tok = (nc - 1) * 256 + kj; if (tok < 0) tok = 0;
      const unsigned short* src =
          C1 + (size_t)(rowB + tok) * C1LD + (arr ? colVi : colVr) + sg * 8;
      bf16x8 v = *(const bf16x8*)src;
#pragma unroll
      for (int j = 0; j < 8; ++j) Vts[arr][sg * 8 + j][row] = (unsigned short)v[j];
    }
    if (wv < 4) { if (c < 5) { PW1(c); } }
    else        { if (c >= 1) { PW1(c - 1); } }
    __syncthreads();
    if (wv < 4) { if (c < 5) { PV1(); } }
    else        { if (c >= 1) { PV1(); } }
  }

#pragma unroll
  for (int fc = 0; fc < 4; ++fc)
#pragma unroll
    for (int r = 0; r < 4; ++r) {
      int m  = rowB + nc * 256 + qw + lh * 4 + r;
      int hd = fc * 16 + lr;
      A2[(size_t)m * 2048 + h * 64 + hd]        = f2bf(oac[0][fc][r] * inv[r]);
      A2[(size_t)m * 2048 + 1024 + h * 64 + hd] = f2bf(oac[1][fc][r] * inv[r]);
    }
}

// ---------------------------------------------------------------------------
extern "C" void kernel_launch(void* const* d_in, const int* in_sizes, int n_in,
                              void* d_out, int out_size, void* d_ws, size_t ws_size,
                              hipStream_t stream) {
  const float* z = (const float*)d_in[0];
  unsigned short* A1 = (unsigned short*)d_ws;                          // 32 MB
  unsigned short* Bp = (unsigned short*)((char*)d_ws + 33554432ull);   // 32 MB
  unsigned short* C1 = (unsigned short*)((char*)d_ws + 67108864ull);   // 96 MB
  float* out = (float*)d_out;

  pa_pack_A<<<4096, 256, 0, stream>>>(z, A1);
  pa_pack_B<<<4096, 256, 0, stream>>>(
      (const float*)d_in[1], (const float*)d_in[2],
      (const float*)d_in[3], (const float*)d_in[4],
      (const float*)d_in[5], (const float*)d_in[6],
      (const float*)d_in[7], (const float*)d_in[8], Bp);
  // QKV projection: [8192x2048] x [2048x6144] -> C1 bf16
  pa_gemm8<0><<<dim3(24, 32), 512, 0, stream>>>(A1, Bp, C1, 2048, 6144);
  // banded attention -> A2 (reuses A1 buffer)
  pa_attn<<<1024, 512, 0, stream>>>(C1, A1);
  // output projection: [8192x2048] x [2048x2048] -> out f32 flat (coalesced)
  pa_gemm8<1><<<dim3(8, 32), 512, 0, stream>>>(A1, Bp + (size_t)6144 * 2048, out,
                                               2048, 2048);
}